// Round 14
// baseline (67.024 us; speedup 1.0000x reference)
//
#include <hip/hip_runtime.h>
#include <hip/hip_bf16.h>
#include <stdint.h>

#define B_N 65536
#define L_N 64
#define E_N 8
#define SPB 64
#define MAXT (B_N/SPB + E_N)   // 1032 max tiles
#define NHB 256                // hist blocks (256 labels each)
#define NPW 608                // pw blocks: (24576+131072)/256
typedef __attribute__((ext_vector_type(4))) float f32x4;
typedef __attribute__((ext_vector_type(8))) short short8;

__device__ __forceinline__ short f2bf(float f){
  union { float f; unsigned u; } v; v.f = f;
  unsigned r = (v.u + 0x7fffu + ((v.u >> 16) & 1u)) >> 16;  // RNE
  return (short)r;
}

// -------- fused prep: blocks 0..255 partial-hist, blocks 256..863 weight-frag prep --------
// A-frag layout per (expert, kstep32): [t 0..15][lane 0..63][j 0..7] bf16, 16 KB
// A elem (lane l, j): m = 16t + (l&15); k = 32s + 4*(l>>4) + (j&3) + 16*(j>>2)
__global__ void k_prep(const int* __restrict__ labels,
                       const float* __restrict__ W0, const float* __restrict__ Wh,
                       unsigned* __restrict__ pcnt,
                       short* __restrict__ wf0, short* __restrict__ wf1){
  const int bid = blockIdx.x, tid = threadIdx.x;
  if(bid < NHB){
    __shared__ unsigned lc[8];
    if(tid < 8) lc[tid] = 0;
    __syncthreads();
    atomicAdd(&lc[labels[bid*256 + tid] & 7], 1u);
    __syncthreads();
    if(tid < 8) pcnt[bid*8 + tid] = lc[tid];
    return;
  }
  int uid = (bid - NHB) * 256 + tid;
  const int NU0 = 8*3*16*64;       // 24576 (layer0: K=96 -> 3 ksteps of 32)
  const int NU1 = 2*8*8*16*64;     // 131072 (hidden: K=256 -> 8 ksteps)
  if(uid < NU0){
    int e = uid / 3072, r = uid % 3072;
    int s = r / 1024, r2 = r % 1024, t = r2 / 64, l = r2 % 64;
    int g = l >> 4, m = 16*t + (l & 15);
    short8 v;
    #pragma unroll
    for(int j=0;j<8;j++){
      int k = 32*s + 4*g + (j & 3) + 16*(j >> 2);
      float f = (k < 67) ? W0[(e*67 + k)*256 + m] : 0.f;
      v[j] = f2bf(f);
    }
    *(short8*)(wf0 + (size_t)uid * 8) = v;
  } else if(uid < NU0 + NU1){
    int u = uid - NU0;
    int lh = u / 65536, r = u % 65536;
    int e = r / 8192, r1 = r % 8192;
    int s = r1 / 1024, r2 = r1 % 1024, t = r2 / 64, l = r2 % 64;
    int g = l >> 4, m = 16*t + (l & 15);
    short8 v;
    #pragma unroll
    for(int j=0;j<8;j++){
      int k = 32*s + 4*g + (j & 3) + 16*(j >> 2);
      v[j] = f2bf(Wh[(((size_t)(lh*8 + e))*256 + k)*256 + m]);
    }
    *(short8*)(wf1 + (size_t)u * 8) = v;
  }
}

// -------- route: each block self-computes scatter bases from pcnt; block 0 also
// emits tile map + KL. --------
__global__ __launch_bounds__(256) void k_route(
    const int* __restrict__ labels, const unsigned* __restrict__ pcnt,
    int* __restrict__ perm, int* __restrict__ te, int* __restrict__ tb,
    int* __restrict__ tl, const float* __restrict__ mu_t,
    const float* __restrict__ lv_t, float* __restrict__ klout){
  __shared__ unsigned spc[NHB*8];
  __shared__ unsigned ptot[256], ppre[256];
  __shared__ unsigned cnt[8], lbase[8], lcnt[8];
  __shared__ int off[9], ts[9];
  __shared__ float fe[8];
  const int bid = blockIdx.x, tid = threadIdx.x;

  #pragma unroll
  for(int i=0;i<8;i++) spc[tid + i*256] = pcnt[tid + i*256];
  if(tid < 8) lcnt[tid] = 0;
  __syncthreads();

  {
    int e = tid >> 5, c = tid & 31;
    unsigned tot = 0, pre = 0;
    #pragma unroll
    for(int j=0;j<8;j++){
      int b = c*8 + j;
      unsigned v = spc[b*8 + e];
      tot += v;
      if(b < bid) pre += v;
    }
    ptot[tid] = tot; ppre[tid] = pre;
  }
  __syncthreads();
  if(tid < 8){
    unsigned t0 = 0, p0 = 0;
    for(int c=0;c<32;c++){ t0 += ptot[tid*32+c]; p0 += ppre[tid*32+c]; }
    cnt[tid] = t0; ppre[tid] = p0;
  }
  __syncthreads();
  if(tid == 0){
    int o = 0, tt = 0;
    for(int e=0;e<8;e++){ off[e]=o; ts[e]=tt; o += (int)cnt[e]; tt += ((int)cnt[e]+SPB-1)/SPB; }
    off[8]=o; ts[8]=tt;
  }
  __syncthreads();
  if(tid < 8) lbase[tid] = (unsigned)off[tid] + ppre[tid];
  __syncthreads();

  int i = bid*256 + tid;
  int e = labels[i] & 7;
  unsigned r = atomicAdd(&lcnt[e], 1u);
  perm[lbase[e] + r] = i;

  if(bid == 0){
    for(int i2=tid; i2<MAXT; i2+=256){
      if(i2 < ts[8]){
        int ee = 0;
        while(ee < 7 && i2 >= ts[ee+1]) ee++;
        te[i2] = ee; tb[i2] = off[ee] + (i2 - ts[ee])*SPB; tl[i2] = off[ee] + (int)cnt[ee];
      } else { te[i2] = 0; tb[i2] = 0; tl[i2] = 0; }
    }
    if(tid < 8){
      float s = 0.f;
      for(int q=0;q<64;q++){
        float m = mu_t[tid*64+q], l = lv_t[tid*64+q];
        s += 1.f + l - m*m - expf(l);
      }
      fe[tid] = s * (float)cnt[tid];
    }
    __syncthreads();
    if(tid == 0){
      float kl = 0.f;
      for(int e2=0;e2<8;e2++) kl += fe[e2];
      klout[0] = -0.5f * kl / (float)B_N;
    }
  }
}

// -------- fused MoE MLP: FEATURE-SPLIT. 64 samples/block (4 sets of 16), 4 waves;
// wave w owns features [64w,64w+64) for ALL sets. Per kstep: 4 A-reads + 4 B-reads
// = 8 KB LDS per wave for 64 samples (0.5 KB/sample, 2x less than r13).
// Layer exchange: wave w's outputs ARE ksteps {2w,2w+1} of next layer's K; the
// C->B map is the same per-lane repack as hb: frag(q,2w+u) elem (l=lane, j) =
// cvt(acc[tile 2u+(j>>2)][set q][reg j&3])  [derived from C row=4g+r / B k=4g+(j&3)+16(j>>2)].
// acc = 4x4 f32x4 = 64 AGPR (same as r13). LDS = 48 (abuf) + 32 (bfrag) = 80 KB
// -> 2 blocks/CU. Biases/Wo read direct from global (L1 broadcast).
__global__ __launch_bounds__(256, 2) void k_mlp(
    const float* __restrict__ x, const float* __restrict__ eps,
    const float* __restrict__ mu_t, const float* __restrict__ lv_t,
    const float* __restrict__ b0, const float* __restrict__ bh,
    const float* __restrict__ Wo, const float* __restrict__ bo,
    const short* __restrict__ wf0, const short* __restrict__ wf1,
    const int* __restrict__ perm, const int* __restrict__ te,
    const int* __restrict__ tb, const int* __restrict__ tl,
    float* __restrict__ out)
{
  __shared__ __align__(16) short abuf[3][8192];     // 48 KB: 3 x 16KB A-tile
  __shared__ __align__(16) short bfrag[4][8][64][8];// 32 KB: [set][kstep][lane][j]

  const int tid  = threadIdx.x;
  const int w    = tid >> 6, lane = tid & 63;
  const int g    = lane >> 4, col = lane & 15;
  const int bid  = blockIdx.x;
  const int e = te[bid], base = tb[bid], lim = tl[bid];
  if(base >= lim) return;

  const float bo_e = bo[e];

  // ---- build x-frags for set w (samples base+16w..+15), write to bfrag[w][0..2] ----
  {
    const int pos = base + w*16 + col;
    const int sid = perm[(pos < lim) ? pos : (lim - 1)];
    #pragma unroll
    for(int s=0;s<3;s++){
      short8 v;
      #pragma unroll
      for(int jh=0;jh<2;jh++){
        #pragma unroll
        for(int q=0;q<4;q++){
          int k = 32*s + 4*g + 16*jh + q;
          float f = 0.f;
          if(k < 3) f = x[sid*3 + k];
          else if(k < 67){
            int zi = k - 3;
            f = mu_t[e*64 + zi] + eps[(size_t)sid*64 + zi] * __expf(0.5f * lv_t[e*64 + zi]);
          }
          v[jh*4 + q] = f2bf(f);
        }
      }
      *(short8*)&bfrag[w][s][lane][0] = v;
    }
  }

  const short* w0e = wf0 + (size_t)e * (3*8192);
  const short* w1e = wf1 + (size_t)(0*8 + e) * (8*8192);
  const short* w2e = wf1 + (size_t)(1*8 + e) * (8*8192);

  f32x4 acc[16];   // acc[t*4+q]: feature-tile t (of wave's 4), sample-set q
  #pragma unroll
  for(int t=0;t<16;t++) acc[t] = (f32x4){0.f,0.f,0.f,0.f};

  auto stage = [&](const short* srcT, int bufidx){
    #pragma unroll
    for(int c=0;c<4;c++){
      const char* gp = (const char*)srcT + c*4096 + tid*16;
      char* lp = (char*)&abuf[bufidx][0] + c*4096 + w*1024;
      __builtin_amdgcn_global_load_lds((const __attribute__((address_space(1))) void*)gp,
                                       (__attribute__((address_space(3))) void*)lp, 16, 0, 0);
    }
  };

  // one kstep: 4 A-frags (wave's feature quarter) x 4 B-frags (all sets)
  auto compute = [&](int bufidx, int s){
    const char* ab = (const char*)&abuf[bufidx][0];
    short8 bq[4], aq[4];
    #pragma unroll
    for(int q=0;q<4;q++) bq[q] = *(const short8*)&bfrag[q][s][lane][0];
    #pragma unroll
    for(int t=0;t<4;t++) aq[t] = *(const short8*)(ab + (w*4 + t)*1024 + lane*16);
    __builtin_amdgcn_s_setprio(1);
    #pragma unroll
    for(int t=0;t<4;t++)
      #pragma unroll
      for(int q=0;q<4;q++)
        acc[t*4+q] = __builtin_amdgcn_mfma_f32_16x16x32_bf16(aq[t], bq[q], acc[t*4+q], 0, 0, 0);
    __builtin_amdgcn_s_setprio(0);
  };

  // bias+relu in place, repack into next layer's B-frags (ksteps 2w, 2w+1)
  auto epilogue = [&](const float* bias_g){
    f32x4 bv[4];
    #pragma unroll
    for(int t=0;t<4;t++) bv[t] = *(const f32x4*)(bias_g + 64*w + 16*t + 4*g);
    #pragma unroll
    for(int t=0;t<4;t++)
      #pragma unroll
      for(int q=0;q<4;q++)
        #pragma unroll
        for(int r=0;r<4;r++){
          float vv = acc[t*4+q][r] + bv[t][r];
          acc[t*4+q][r] = vv > 0.f ? vv : 0.f;
        }
    #pragma unroll
    for(int u=0;u<2;u++)
      #pragma unroll
      for(int q=0;q<4;q++){
        short8 h;
        #pragma unroll
        for(int r=0;r<4;r++){
          h[r]   = f2bf(acc[(2*u)*4   + q][r]);
          h[4+r] = f2bf(acc[(2*u+1)*4 + q][r]);
        }
        *(short8*)&bfrag[q][2*w+u][lane][0] = h;
      }
    #pragma unroll
    for(int t=0;t<16;t++) acc[t] = (f32x4){0.f,0.f,0.f,0.f};
  };

  // tile T: 0..2 layer0 (bfrag s=T), 3..10 layer1 (s=T-3), 11..18 layer2 (s=T-11)
  #define SRC_OF(u) ((u) < 3 ? (w0e + (u)*8192) : (u) < 11 ? (w1e + ((u)-3)*8192) \
                             : (w2e + ((u)-11)*8192))
  #define DO_TILE(T, S)                                                           \
    { if((T) < 17){ asm volatile("s_waitcnt vmcnt(4) lgkmcnt(0)" ::: "memory"); } \
      else        { asm volatile("s_waitcnt vmcnt(0) lgkmcnt(0)" ::: "memory"); } \
      __builtin_amdgcn_s_barrier();                                               \
      if((T) + 2 < 19) stage(SRC_OF((T)+2 < 19 ? (T)+2 : 18), ((T)+2) % 3);       \
      compute((T) % 3, (S)); }
  #define LAYER_FENCE                                                             \
    asm volatile("s_waitcnt lgkmcnt(0)" ::: "memory");                            \
    __builtin_amdgcn_s_barrier();

  stage(SRC_OF(0), 0);
  stage(SRC_OF(1), 1);

  // ---- layer 0 ----
  DO_TILE(0, 0)
  DO_TILE(1, 1)
  DO_TILE(2, 2)
  LAYER_FENCE                      // all waves done reading x-frags
  epilogue(b0 + e*256);            // next wall's lgkm+barrier publishes writes

  // ---- layer 1 ----
  DO_TILE(3,  0)
  DO_TILE(4,  1)
  DO_TILE(5,  2)
  DO_TILE(6,  3)
  DO_TILE(7,  4)
  DO_TILE(8,  5)
  DO_TILE(9,  6)
  DO_TILE(10, 7)
  LAYER_FENCE
  epilogue(bh + e*256);

  // ---- layer 2 ----
  DO_TILE(11, 0)
  DO_TILE(12, 1)
  DO_TILE(13, 2)
  DO_TILE(14, 3)
  DO_TILE(15, 4)
  DO_TILE(16, 5)
  DO_TILE(17, 6)
  DO_TILE(18, 7)
  #undef DO_TILE
  #undef SRC_OF

  // ---- output: bias+relu, dot with Wo over wave's 64 features, cross-wave sum ----
  LAYER_FENCE                      // done reading bfrag; safe to alias as odot
  float* odot = (float*)&bfrag[0][0][0][0];   // [w][q][col] = 256 floats
  {
    const float* bias_g = bh + (8 + e)*256;
    const float* wo_g   = Wo + e*256;
    f32x4 bv[4], wv[4];
    #pragma unroll
    for(int t=0;t<4;t++){
      bv[t] = *(const f32x4*)(bias_g + 64*w + 16*t + 4*g);
      wv[t] = *(const f32x4*)(wo_g   + 64*w + 16*t + 4*g);
    }
    #pragma unroll
    for(int q=0;q<4;q++){
      float d = 0.f;
      #pragma unroll
      for(int t=0;t<4;t++)
        #pragma unroll
        for(int r=0;r<4;r++){
          float vv = acc[t*4+q][r] + bv[t][r];
          vv = vv > 0.f ? vv : 0.f;
          d += vv * wv[t][r];
        }
      d += __shfl_xor(d, 16, 64);
      d += __shfl_xor(d, 32, 64);
      if(g == 0) odot[(w*4 + q)*16 + col] = d;
    }
  }
  LAYER_FENCE
  if(tid < 64){
    int q = tid >> 4, c = tid & 15;
    float s = odot[(0*4+q)*16+c] + odot[(1*4+q)*16+c]
            + odot[(2*4+q)*16+c] + odot[(3*4+q)*16+c];
    int p2 = base + tid;
    if(p2 < lim) out[perm[p2]] = s + bo_e;
  }
  #undef LAYER_FENCE
}

extern "C" void kernel_launch(void* const* d_in, const int* in_sizes, int n_in,
                              void* d_out, int out_size, void* d_ws, size_t ws_size,
                              hipStream_t stream){
  (void)in_sizes; (void)n_in; (void)out_size; (void)ws_size;
  const float* x   = (const float*)d_in[0];
  const int*   lab = (const int*)d_in[1];
  const float* eps = (const float*)d_in[2];
  const float* mu  = (const float*)d_in[3];
  const float* lv  = (const float*)d_in[4];
  const float* W0  = (const float*)d_in[5];
  const float* b0  = (const float*)d_in[6];
  const float* Wh  = (const float*)d_in[7];
  const float* bh  = (const float*)d_in[8];
  const float* Wo  = (const float*)d_in[9];
  const float* bo  = (const float*)d_in[10];
  float* out = (float*)d_out;

  char* ws = (char*)d_ws;
  unsigned* pcnt  = (unsigned*)(ws + 128);     // 256 x 8 u32 = 8 KB
  int* te   = (int*)(ws + 16640);
  int* tb   = (int*)(ws + 16640 + 4*MAXT);
  int* tl   = (int*)(ws + 16640 + 8*MAXT);
  int* perm = (int*)(ws + 32768);              // 256 KB
  short* wf0 = (short*)(ws + 294912);          // 8 e x 3 ks x 16 KB = 384 KB
  short* wf1 = (short*)(ws + 688128);          // 2 x 8 e x 8 ks x 16 KB = 2 MB

  k_prep<<<NHB + NPW, 256, 0, stream>>>(lab, W0, Wh, pcnt, wf0, wf1);
  k_route<<<NHB, 256, 0, stream>>>(lab, pcnt, perm, te, tb, tl, mu, lv, out + B_N);
  k_mlp<<<MAXT, 256, 0, stream>>>(x, eps, mu, lv, b0, bh, Wo, bo,
                                  wf0, wf1, perm, te, tb, tl, out);
}

// Round 15
// 63.570 us; speedup vs baseline: 1.0543x; 1.0543x over previous
//
#include <hip/hip_runtime.h>
#include <hip/hip_bf16.h>
#include <stdint.h>

#define B_N 65536
#define L_N 64
#define E_N 8
#define SPB 64
#define MAXT (B_N/SPB + E_N)   // 1032 max tiles
#define NHB 256                // hist blocks (256 labels each)
#define NPW 608                // pw blocks: (24576+131072)/256
typedef __attribute__((ext_vector_type(4))) float f32x4;
typedef __attribute__((ext_vector_type(8))) short short8;

__device__ __forceinline__ short f2bf(float f){
  union { float f; unsigned u; } v; v.f = f;
  unsigned r = (v.u + 0x7fffu + ((v.u >> 16) & 1u)) >> 16;  // RNE
  return (short)r;
}

// -------- fused prep: blocks 0..255 partial-hist, blocks 256..863 weight-frag prep --------
// A-frag layout per (expert, kstep32): [t 0..15][lane 0..63][j 0..7] bf16, 16 KB
// A elem (lane l, j): m = 16t + (l&15); k = 32s + 4*(l>>4) + (j&3) + 16*(j>>2)
__global__ void k_prep(const int* __restrict__ labels,
                       const float* __restrict__ W0, const float* __restrict__ Wh,
                       unsigned* __restrict__ pcnt,
                       short* __restrict__ wf0, short* __restrict__ wf1){
  const int bid = blockIdx.x, tid = threadIdx.x;
  if(bid < NHB){
    __shared__ unsigned lc[8];
    if(tid < 8) lc[tid] = 0;
    __syncthreads();
    atomicAdd(&lc[labels[bid*256 + tid] & 7], 1u);
    __syncthreads();
    if(tid < 8) pcnt[bid*8 + tid] = lc[tid];
    return;
  }
  int uid = (bid - NHB) * 256 + tid;
  const int NU0 = 8*3*16*64;       // 24576 (layer0: K=96 -> 3 ksteps of 32)
  const int NU1 = 2*8*8*16*64;     // 131072 (hidden: K=256 -> 8 ksteps)
  if(uid < NU0){
    int e = uid / 3072, r = uid % 3072;
    int s = r / 1024, r2 = r % 1024, t = r2 / 64, l = r2 % 64;
    int g = l >> 4, m = 16*t + (l & 15);
    short8 v;
    #pragma unroll
    for(int j=0;j<8;j++){
      int k = 32*s + 4*g + (j & 3) + 16*(j >> 2);
      float f = (k < 67) ? W0[(e*67 + k)*256 + m] : 0.f;
      v[j] = f2bf(f);
    }
    *(short8*)(wf0 + (size_t)uid * 8) = v;
  } else if(uid < NU0 + NU1){
    int u = uid - NU0;
    int lh = u / 65536, r = u % 65536;
    int e = r / 8192, r1 = r % 8192;
    int s = r1 / 1024, r2 = r1 % 1024, t = r2 / 64, l = r2 % 64;
    int g = l >> 4, m = 16*t + (l & 15);
    short8 v;
    #pragma unroll
    for(int j=0;j<8;j++){
      int k = 32*s + 4*g + (j & 3) + 16*(j >> 2);
      v[j] = f2bf(Wh[(((size_t)(lh*8 + e))*256 + k)*256 + m]);
    }
    *(short8*)(wf1 + (size_t)u * 8) = v;
  }
}

// -------- route: each block self-computes scatter bases from pcnt; block 0 also
// emits tile map + KL. --------
__global__ __launch_bounds__(256) void k_route(
    const int* __restrict__ labels, const unsigned* __restrict__ pcnt,
    int* __restrict__ perm, int* __restrict__ te, int* __restrict__ tb,
    int* __restrict__ tl, const float* __restrict__ mu_t,
    const float* __restrict__ lv_t, float* __restrict__ klout){
  __shared__ unsigned spc[NHB*8];
  __shared__ unsigned ptot[256], ppre[256];
  __shared__ unsigned cnt[8], lbase[8], lcnt[8];
  __shared__ int off[9], ts[9];
  __shared__ float fe[8];
  const int bid = blockIdx.x, tid = threadIdx.x;

  #pragma unroll
  for(int i=0;i<8;i++) spc[tid + i*256] = pcnt[tid + i*256];
  if(tid < 8) lcnt[tid] = 0;
  __syncthreads();

  {
    int e = tid >> 5, c = tid & 31;
    unsigned tot = 0, pre = 0;
    #pragma unroll
    for(int j=0;j<8;j++){
      int b = c*8 + j;
      unsigned v = spc[b*8 + e];
      tot += v;
      if(b < bid) pre += v;
    }
    ptot[tid] = tot; ppre[tid] = pre;
  }
  __syncthreads();
  if(tid < 8){
    unsigned t0 = 0, p0 = 0;
    for(int c=0;c<32;c++){ t0 += ptot[tid*32+c]; p0 += ppre[tid*32+c]; }
    cnt[tid] = t0; ppre[tid] = p0;
  }
  __syncthreads();
  if(tid == 0){
    int o = 0, tt = 0;
    for(int e=0;e<8;e++){ off[e]=o; ts[e]=tt; o += (int)cnt[e]; tt += ((int)cnt[e]+SPB-1)/SPB; }
    off[8]=o; ts[8]=tt;
  }
  __syncthreads();
  if(tid < 8) lbase[tid] = (unsigned)off[tid] + ppre[tid];
  __syncthreads();

  int i = bid*256 + tid;
  int e = labels[i] & 7;
  unsigned r = atomicAdd(&lcnt[e], 1u);
  perm[lbase[e] + r] = i;

  if(bid == 0){
    for(int i2=tid; i2<MAXT; i2+=256){
      if(i2 < ts[8]){
        int ee = 0;
        while(ee < 7 && i2 >= ts[ee+1]) ee++;
        te[i2] = ee; tb[i2] = off[ee] + (i2 - ts[ee])*SPB; tl[i2] = off[ee] + (int)cnt[ee];
      } else { te[i2] = 0; tb[i2] = 0; tl[i2] = 0; }
    }
    if(tid < 8){
      float s = 0.f;
      for(int q=0;q<64;q++){
        float m = mu_t[tid*64+q], l = lv_t[tid*64+q];
        s += 1.f + l - m*m - expf(l);
      }
      fe[tid] = s * (float)cnt[tid];
    }
    __syncthreads();
    if(tid == 0){
      float kl = 0.f;
      for(int e2=0;e2<8;e2++) kl += fe[e2];
      klout[0] = -0.5f * kl / (float)B_N;
    }
  }
}

// -------- fused MoE MLP: 16 samples/wave (16x16x32), 64/block, DOUBLE-buffered,
// (256,4) -> reg cap 128 (64 acc + 64 arch; ~20 cold regs spill/remat), 4 blocks/CU.
// LDS 2x16KB abuf + 4KB bias = 36.25KB -> 4 co-resident blocks = 16 waves/CU.
// Prefetch depth 1 wall (~540ns) >> L2-hit latency (~200cyc); staging is 94% L2-hit
// (FETCH 20MB vs 313MB staged).
__global__ __launch_bounds__(256, 4) void k_mlp(
    const float* __restrict__ x, const float* __restrict__ eps,
    const float* __restrict__ mu_t, const float* __restrict__ lv_t,
    const float* __restrict__ b0, const float* __restrict__ bh,
    const float* __restrict__ Wo, const float* __restrict__ bo,
    const short* __restrict__ wf0, const short* __restrict__ wf1,
    const int* __restrict__ perm, const int* __restrict__ te,
    const int* __restrict__ tb, const int* __restrict__ tl,
    float* __restrict__ out)
{
  __shared__ __align__(16) short abuf[2][8192];   // 2 x 16KB A-tile (1 kstep of K=32)
  __shared__ __align__(16) float bias_lds[3][256];
  __shared__ __align__(16) float wo_lds[256];

  const int tid  = threadIdx.x;
  const int w    = tid >> 6, lane = tid & 63;
  const int g    = lane >> 4, col = lane & 15;
  const int bid  = blockIdx.x;
  const int e = te[bid], base = tb[bid], lim = tl[bid];
  if(base >= lim) return;

  bias_lds[0][tid] = b0[e*256 + tid];
  bias_lds[1][tid] = bh[e*256 + tid];
  bias_lds[2][tid] = bh[(8 + e)*256 + tid];
  wo_lds[tid]      = Wo[e*256 + tid];

  const int pos = base + w*16 + col;      // each of 4 waves owns 16 samples
  const bool valid = pos < lim;
  const int sid = perm[valid ? pos : (lim - 1)];
  const float bo_e = bo[e];

  // ---- layer-0 B-fragments (x_in^T), K=96 padded, in registers ----
  short8 bx[3];
  #pragma unroll
  for(int s=0;s<3;s++){
    short8 v;
    #pragma unroll
    for(int jh=0;jh<2;jh++){
      #pragma unroll
      for(int q=0;q<4;q++){
        int k = 32*s + 4*g + 16*jh + q;
        float f = 0.f;
        if(k < 3) f = x[sid*3 + k];
        else if(k < 67){
          int zi = k - 3;
          f = mu_t[e*64 + zi] + eps[(size_t)sid*64 + zi] * __expf(0.5f * lv_t[e*64 + zi]);
        }
        v[jh*4 + q] = f2bf(f);
      }
    }
    bx[s] = v;
  }

  const short* w0e = wf0 + (size_t)e * (3*8192);
  const short* w1e = wf1 + (size_t)(0*8 + e) * (8*8192);
  const short* w2e = wf1 + (size_t)(1*8 + e) * (8*8192);

  f32x4 acc[16];
  #pragma unroll
  for(int t=0;t<16;t++) acc[t] = (f32x4){0.f,0.f,0.f,0.f};
  short8 hb[8];

  auto stage = [&](const short* srcT, int bufidx){
    #pragma unroll
    for(int c=0;c<4;c++){
      const char* gp = (const char*)srcT + c*4096 + tid*16;          // per-lane src
      char* lp = (char*)&abuf[bufidx][0] + c*4096 + w*1024;          // wave-uniform dst
      __builtin_amdgcn_global_load_lds((const __attribute__((address_space(1))) void*)gp,
                                       (__attribute__((address_space(3))) void*)lp, 16, 0, 0);
    }
  };

  auto compute = [&](int bufidx, short8 b){
    const char* ab = (const char*)&abuf[bufidx][0];
    __builtin_amdgcn_s_setprio(1);                    // T5: favor MFMA-issuing wave
    #pragma unroll
    for(int t=0;t<16;t++){
      short8 a = *(const short8*)(ab + t*1024 + lane*16);
      acc[t] = __builtin_amdgcn_mfma_f32_16x16x32_bf16(a, b, acc[t], 0, 0, 0);
    }
    __builtin_amdgcn_s_setprio(0);
  };

  auto epilogue = [&](const float* bias_row){
    #pragma unroll
    for(int t=0;t<16;t++){
      f32x4 b4 = *(const f32x4*)(bias_row + 16*t + 4*g);
      #pragma unroll
      for(int r=0;r<4;r++){
        float vv = acc[t][r] + b4[r];
        acc[t][r] = vv > 0.f ? vv : 0.f;
      }
    }
    #pragma unroll
    for(int s=0;s<8;s++){
      short8 h;
      #pragma unroll
      for(int r=0;r<4;r++){ h[r] = f2bf(acc[2*s][r]); h[4+r] = f2bf(acc[2*s+1][r]); }
      hb[s] = h;
    }
    #pragma unroll
    for(int t=0;t<16;t++) acc[t] = (f32x4){0.f,0.f,0.f,0.f};
  };

  // tile t: 0..2 = layer0, 3..10 = layer1, 11..18 = layer2 (K=32 each)
  // dbuf: wait for stage(T) (issued 1 wall ago), barrier, issue stage(T+1) into
  // buf (T+1)&1 (all waves passed barrier => done reading it), compute buf T&1.
  #define SRC_OF(u) ((u) < 3 ? (w0e + (u)*8192) : (u) < 11 ? (w1e + ((u)-3)*8192) \
                             : (w2e + ((u)-11)*8192))
  #define DO_TILE(T, H)                                                           \
    { asm volatile("s_waitcnt vmcnt(0) lgkmcnt(0)" ::: "memory");                 \
      __builtin_amdgcn_s_barrier();                                               \
      if((T) + 1 < 19) stage(SRC_OF((T)+1 < 19 ? (T)+1 : 18), ((T)+1) & 1);       \
      compute((T) & 1, H); }

  stage(SRC_OF(0), 0);

  // ---- layer 0 ----
  DO_TILE(0, bx[0])
  DO_TILE(1, bx[1])
  DO_TILE(2, bx[2])
  epilogue(&bias_lds[0][0]);

  // ---- layer 1 ----
  DO_TILE(3,  hb[0])
  DO_TILE(4,  hb[1])
  DO_TILE(5,  hb[2])
  DO_TILE(6,  hb[3])
  DO_TILE(7,  hb[4])
  DO_TILE(8,  hb[5])
  DO_TILE(9,  hb[6])
  DO_TILE(10, hb[7])
  epilogue(&bias_lds[1][0]);

  // ---- layer 2 ----
  DO_TILE(11, hb[0])
  DO_TILE(12, hb[1])
  DO_TILE(13, hb[2])
  DO_TILE(14, hb[3])
  DO_TILE(15, hb[4])
  DO_TILE(16, hb[5])
  DO_TILE(17, hb[6])
  DO_TILE(18, hb[7])
  #undef DO_TILE
  #undef SRC_OF

  // ---- output layer: bias+relu, dot with Wo, reduce across g groups ----
  float dot = 0.f;
  #pragma unroll
  for(int t=0;t<16;t++){
    f32x4 b4 = *(const f32x4*)(&bias_lds[2][16*t + 4*g]);
    f32x4 w4 = *(const f32x4*)(&wo_lds[16*t + 4*g]);
    #pragma unroll
    for(int r=0;r<4;r++){
      float vv = acc[t][r] + b4[r];
      vv = vv > 0.f ? vv : 0.f;
      dot += vv * w4[r];
    }
  }
  dot += __shfl_xor(dot, 16, 64);
  dot += __shfl_xor(dot, 32, 64);
  if(g == 0 && valid) out[sid] = dot + bo_e;
}

extern "C" void kernel_launch(void* const* d_in, const int* in_sizes, int n_in,
                              void* d_out, int out_size, void* d_ws, size_t ws_size,
                              hipStream_t stream){
  (void)in_sizes; (void)n_in; (void)out_size; (void)ws_size;
  const float* x   = (const float*)d_in[0];
  const int*   lab = (const int*)d_in[1];
  const float* eps = (const float*)d_in[2];
  const float* mu  = (const float*)d_in[3];
  const float* lv  = (const float*)d_in[4];
  const float* W0  = (const float*)d_in[5];
  const float* b0  = (const float*)d_in[6];
  const float* Wh  = (const float*)d_in[7];
  const float* bh  = (const float*)d_in[8];
  const float* Wo  = (const float*)d_in[9];
  const float* bo  = (const float*)d_in[10];
  float* out = (float*)d_out;

  char* ws = (char*)d_ws;
  unsigned* pcnt  = (unsigned*)(ws + 128);     // 256 x 8 u32 = 8 KB
  int* te   = (int*)(ws + 16640);
  int* tb   = (int*)(ws + 16640 + 4*MAXT);
  int* tl   = (int*)(ws + 16640 + 8*MAXT);
  int* perm = (int*)(ws + 32768);              // 256 KB
  short* wf0 = (short*)(ws + 294912);          // 8 e x 3 ks x 16 KB = 384 KB
  short* wf1 = (short*)(ws + 688128);          // 2 x 8 e x 8 ks x 16 KB = 2 MB

  k_prep<<<NHB + NPW, 256, 0, stream>>>(lab, W0, Wh, pcnt, wf0, wf1);
  k_route<<<NHB, 256, 0, stream>>>(lab, pcnt, perm, te, tb, tl, mu, lv, out + B_N);
  k_mlp<<<MAXT, 256, 0, stream>>>(x, eps, mu, lv, b0, bh, Wo, bo,
                                  wf0, wf1, perm, te, tb, tl, out);
}

// Round 16
// 52.559 us; speedup vs baseline: 1.2752x; 1.2095x over previous
//
#include <hip/hip_runtime.h>
#include <hip/hip_bf16.h>
#include <stdint.h>

#define B_N 65536
#define L_N 64
#define E_N 8
#define SPB 64
#define MAXT (B_N/SPB + E_N)   // 1032 max tiles
#define NHB 256                // hist blocks (256 labels each)
#define NPW 608                // pw blocks: (24576+131072)/256
typedef __attribute__((ext_vector_type(4))) float f32x4;
typedef __attribute__((ext_vector_type(8))) short short8;

__device__ __forceinline__ short f2bf(float f){
  union { float f; unsigned u; } v; v.f = f;
  unsigned r = (v.u + 0x7fffu + ((v.u >> 16) & 1u)) >> 16;  // RNE
  return (short)r;
}

// -------- fused prep: blocks 0..255 partial-hist, blocks 256..863 weight-frag prep --------
// A-frag layout per (expert, kstep32): [t 0..15][lane 0..63][j 0..7] bf16, 16 KB
// A elem (lane l, j): m = 16t + (l&15); k = 32s + 4*(l>>4) + (j&3) + 16*(j>>2)
__global__ void k_prep(const int* __restrict__ labels,
                       const float* __restrict__ W0, const float* __restrict__ Wh,
                       unsigned* __restrict__ pcnt,
                       short* __restrict__ wf0, short* __restrict__ wf1){
  const int bid = blockIdx.x, tid = threadIdx.x;
  if(bid < NHB){
    __shared__ unsigned lc[8];
    if(tid < 8) lc[tid] = 0;
    __syncthreads();
    atomicAdd(&lc[labels[bid*256 + tid] & 7], 1u);
    __syncthreads();
    if(tid < 8) pcnt[bid*8 + tid] = lc[tid];
    return;
  }
  int uid = (bid - NHB) * 256 + tid;
  const int NU0 = 8*3*16*64;       // 24576 (layer0: K=96 -> 3 ksteps of 32)
  const int NU1 = 2*8*8*16*64;     // 131072 (hidden: K=256 -> 8 ksteps)
  if(uid < NU0){
    int e = uid / 3072, r = uid % 3072;
    int s = r / 1024, r2 = r % 1024, t = r2 / 64, l = r2 % 64;
    int g = l >> 4, m = 16*t + (l & 15);
    short8 v;
    #pragma unroll
    for(int j=0;j<8;j++){
      int k = 32*s + 4*g + (j & 3) + 16*(j >> 2);
      float f = (k < 67) ? W0[(e*67 + k)*256 + m] : 0.f;
      v[j] = f2bf(f);
    }
    *(short8*)(wf0 + (size_t)uid * 8) = v;
  } else if(uid < NU0 + NU1){
    int u = uid - NU0;
    int lh = u / 65536, r = u % 65536;
    int e = r / 8192, r1 = r % 8192;
    int s = r1 / 1024, r2 = r1 % 1024, t = r2 / 64, l = r2 % 64;
    int g = l >> 4, m = 16*t + (l & 15);
    short8 v;
    #pragma unroll
    for(int j=0;j<8;j++){
      int k = 32*s + 4*g + (j & 3) + 16*(j >> 2);
      v[j] = f2bf(Wh[(((size_t)(lh*8 + e))*256 + k)*256 + m]);
    }
    *(short8*)(wf1 + (size_t)u * 8) = v;
  }
}

// -------- route: each block self-computes scatter bases from pcnt; block 0 also
// emits tile map + KL. --------
__global__ __launch_bounds__(256) void k_route(
    const int* __restrict__ labels, const unsigned* __restrict__ pcnt,
    int* __restrict__ perm, int* __restrict__ te, int* __restrict__ tb,
    int* __restrict__ tl, const float* __restrict__ mu_t,
    const float* __restrict__ lv_t, float* __restrict__ klout){
  __shared__ unsigned spc[NHB*8];
  __shared__ unsigned ptot[256], ppre[256];
  __shared__ unsigned cnt[8], lbase[8], lcnt[8];
  __shared__ int off[9], ts[9];
  __shared__ float fe[8];
  const int bid = blockIdx.x, tid = threadIdx.x;

  #pragma unroll
  for(int i=0;i<8;i++) spc[tid + i*256] = pcnt[tid + i*256];
  if(tid < 8) lcnt[tid] = 0;
  __syncthreads();

  {
    int e = tid >> 5, c = tid & 31;
    unsigned tot = 0, pre = 0;
    #pragma unroll
    for(int j=0;j<8;j++){
      int b = c*8 + j;
      unsigned v = spc[b*8 + e];
      tot += v;
      if(b < bid) pre += v;
    }
    ptot[tid] = tot; ppre[tid] = pre;
  }
  __syncthreads();
  if(tid < 8){
    unsigned t0 = 0, p0 = 0;
    for(int c=0;c<32;c++){ t0 += ptot[tid*32+c]; p0 += ppre[tid*32+c]; }
    cnt[tid] = t0; ppre[tid] = p0;
  }
  __syncthreads();
  if(tid == 0){
    int o = 0, tt = 0;
    for(int e=0;e<8;e++){ off[e]=o; ts[e]=tt; o += (int)cnt[e]; tt += ((int)cnt[e]+SPB-1)/SPB; }
    off[8]=o; ts[8]=tt;
  }
  __syncthreads();
  if(tid < 8) lbase[tid] = (unsigned)off[tid] + ppre[tid];
  __syncthreads();

  int i = bid*256 + tid;
  int e = labels[i] & 7;
  unsigned r = atomicAdd(&lcnt[e], 1u);
  perm[lbase[e] + r] = i;

  if(bid == 0){
    for(int i2=tid; i2<MAXT; i2+=256){
      if(i2 < ts[8]){
        int ee = 0;
        while(ee < 7 && i2 >= ts[ee+1]) ee++;
        te[i2] = ee; tb[i2] = off[ee] + (i2 - ts[ee])*SPB; tl[i2] = off[ee] + (int)cnt[ee];
      } else { te[i2] = 0; tb[i2] = 0; tl[i2] = 0; }
    }
    if(tid < 8){
      float s = 0.f;
      for(int q=0;q<64;q++){
        float m = mu_t[tid*64+q], l = lv_t[tid*64+q];
        s += 1.f + l - m*m - expf(l);
      }
      fe[tid] = s * (float)cnt[tid];
    }
    __syncthreads();
    if(tid == 0){
      float kl = 0.f;
      for(int e2=0;e2<8;e2++) kl += fe[e2];
      klout[0] = -0.5f * kl / (float)B_N;
    }
  }
}

// -------- fused MoE MLP: 16 samples/wave (16x16x32), 64/block, 3 blocks/CU --------
// Measured optimum of the explored design space (r10-r15): 148 regs/wave (84 arch
// + 64 acc) and 52 KB LDS jointly pin 12 waves/CU; dual-B (r11), feature-split
// (r14) and 4-block reg-cap (r15) all regressed via spill or lost co-residency.
__global__ __launch_bounds__(256, 3) void k_mlp(
    const float* __restrict__ x, const float* __restrict__ eps,
    const float* __restrict__ mu_t, const float* __restrict__ lv_t,
    const float* __restrict__ b0, const float* __restrict__ bh,
    const float* __restrict__ Wo, const float* __restrict__ bo,
    const short* __restrict__ wf0, const short* __restrict__ wf1,
    const int* __restrict__ perm, const int* __restrict__ te,
    const int* __restrict__ tb, const int* __restrict__ tl,
    float* __restrict__ out)
{
  __shared__ __align__(16) short abuf[3][8192];   // 3 x 16KB A-tile (1 kstep of K=32)
  __shared__ __align__(16) float bias_lds[3][256];
  __shared__ __align__(16) float wo_lds[256];

  const int tid  = threadIdx.x;
  const int w    = tid >> 6, lane = tid & 63;
  const int g    = lane >> 4, col = lane & 15;
  const int bid  = blockIdx.x;
  const int e = te[bid], base = tb[bid], lim = tl[bid];
  if(base >= lim) return;

  bias_lds[0][tid] = b0[e*256 + tid];
  bias_lds[1][tid] = bh[e*256 + tid];
  bias_lds[2][tid] = bh[(8 + e)*256 + tid];
  wo_lds[tid]      = Wo[e*256 + tid];

  const int pos = base + w*16 + col;      // each of 4 waves owns 16 samples
  const bool valid = pos < lim;
  const int sid = perm[valid ? pos : (lim - 1)];
  const float bo_e = bo[e];

  // ---- layer-0 B-fragments (x_in^T), K=96 padded, in registers ----
  short8 bx[3];
  #pragma unroll
  for(int s=0;s<3;s++){
    short8 v;
    #pragma unroll
    for(int jh=0;jh<2;jh++){
      #pragma unroll
      for(int q=0;q<4;q++){
        int k = 32*s + 4*g + 16*jh + q;
        float f = 0.f;
        if(k < 3) f = x[sid*3 + k];
        else if(k < 67){
          int zi = k - 3;
          f = mu_t[e*64 + zi] + eps[(size_t)sid*64 + zi] * __expf(0.5f * lv_t[e*64 + zi]);
        }
        v[jh*4 + q] = f2bf(f);
      }
    }
    bx[s] = v;
  }

  const short* w0e = wf0 + (size_t)e * (3*8192);
  const short* w1e = wf1 + (size_t)(0*8 + e) * (8*8192);
  const short* w2e = wf1 + (size_t)(1*8 + e) * (8*8192);

  f32x4 acc[16];
  #pragma unroll
  for(int t=0;t<16;t++) acc[t] = (f32x4){0.f,0.f,0.f,0.f};
  short8 hb[8];

  auto stage = [&](const short* srcT, int bufidx){
    #pragma unroll
    for(int c=0;c<4;c++){
      const char* gp = (const char*)srcT + c*4096 + tid*16;          // per-lane src
      char* lp = (char*)&abuf[bufidx][0] + c*4096 + w*1024;          // wave-uniform dst
      __builtin_amdgcn_global_load_lds((const __attribute__((address_space(1))) void*)gp,
                                       (__attribute__((address_space(3))) void*)lp, 16, 0, 0);
    }
  };

  auto compute = [&](int bufidx, short8 b){
    const char* ab = (const char*)&abuf[bufidx][0];
    __builtin_amdgcn_s_setprio(1);                    // T5: favor MFMA-issuing wave
    #pragma unroll
    for(int t=0;t<16;t++){
      short8 a = *(const short8*)(ab + t*1024 + lane*16);
      acc[t] = __builtin_amdgcn_mfma_f32_16x16x32_bf16(a, b, acc[t], 0, 0, 0);
    }
    __builtin_amdgcn_s_setprio(0);
  };

  auto epilogue = [&](const float* bias_row){
    #pragma unroll
    for(int t=0;t<16;t++){
      f32x4 b4 = *(const f32x4*)(bias_row + 16*t + 4*g);
      #pragma unroll
      for(int r=0;r<4;r++){
        float vv = acc[t][r] + b4[r];
        acc[t][r] = vv > 0.f ? vv : 0.f;
      }
    }
    #pragma unroll
    for(int s=0;s<8;s++){
      short8 h;
      #pragma unroll
      for(int r=0;r<4;r++){ h[r] = f2bf(acc[2*s][r]); h[4+r] = f2bf(acc[2*s+1][r]); }
      hb[s] = h;
    }
    #pragma unroll
    for(int t=0;t<16;t++) acc[t] = (f32x4){0.f,0.f,0.f,0.f};
  };

  // tile t: 0..2 = layer0, 3..10 = layer1, 11..18 = layer2 (K=32 each)
  #define SRC_OF(u) ((u) < 3 ? (w0e + (u)*8192) : (u) < 11 ? (w1e + ((u)-3)*8192) \
                             : (w2e + ((u)-11)*8192))
  #define DO_TILE(T, H)                                                           \
    { if((T) < 17){ asm volatile("s_waitcnt vmcnt(4) lgkmcnt(0)" ::: "memory"); } \
      else        { asm volatile("s_waitcnt vmcnt(0) lgkmcnt(0)" ::: "memory"); } \
      __builtin_amdgcn_s_barrier();                                               \
      if((T) + 2 < 19) stage(SRC_OF((T)+2 < 19 ? (T)+2 : 18), ((T)+2) % 3);       \
      compute((T) % 3, H); }

  stage(SRC_OF(0), 0);
  stage(SRC_OF(1), 1);

  // ---- layer 0 ----
  DO_TILE(0, bx[0])
  DO_TILE(1, bx[1])
  DO_TILE(2, bx[2])
  epilogue(&bias_lds[0][0]);

  // ---- layer 1 ----
  DO_TILE(3,  hb[0])
  DO_TILE(4,  hb[1])
  DO_TILE(5,  hb[2])
  DO_TILE(6,  hb[3])
  DO_TILE(7,  hb[4])
  DO_TILE(8,  hb[5])
  DO_TILE(9,  hb[6])
  DO_TILE(10, hb[7])
  epilogue(&bias_lds[1][0]);

  // ---- layer 2 ----
  DO_TILE(11, hb[0])
  DO_TILE(12, hb[1])
  DO_TILE(13, hb[2])
  DO_TILE(14, hb[3])
  DO_TILE(15, hb[4])
  DO_TILE(16, hb[5])
  DO_TILE(17, hb[6])
  DO_TILE(18, hb[7])
  #undef DO_TILE
  #undef SRC_OF

  // ---- output layer: bias+relu, dot with Wo, reduce across g groups ----
  float dot = 0.f;
  #pragma unroll
  for(int t=0;t<16;t++){
    f32x4 b4 = *(const f32x4*)(&bias_lds[2][16*t + 4*g]);
    f32x4 w4 = *(const f32x4*)(&wo_lds[16*t + 4*g]);
    #pragma unroll
    for(int r=0;r<4;r++){
      float vv = acc[t][r] + b4[r];
      vv = vv > 0.f ? vv : 0.f;
      dot += vv * w4[r];
    }
  }
  dot += __shfl_xor(dot, 16, 64);
  dot += __shfl_xor(dot, 32, 64);
  if(g == 0 && valid) out[sid] = dot + bo_e;
}

extern "C" void kernel_launch(void* const* d_in, const int* in_sizes, int n_in,
                              void* d_out, int out_size, void* d_ws, size_t ws_size,
                              hipStream_t stream){
  (void)in_sizes; (void)n_in; (void)out_size; (void)ws_size;
  const float* x   = (const float*)d_in[0];
  const int*   lab = (const int*)d_in[1];
  const float* eps = (const float*)d_in[2];
  const float* mu  = (const float*)d_in[3];
  const float* lv  = (const float*)d_in[4];
  const float* W0  = (const float*)d_in[5];
  const float* b0  = (const float*)d_in[6];
  const float* Wh  = (const float*)d_in[7];
  const float* bh  = (const float*)d_in[8];
  const float* Wo  = (const float*)d_in[9];
  const float* bo  = (const float*)d_in[10];
  float* out = (float*)d_out;

  char* ws = (char*)d_ws;
  unsigned* pcnt  = (unsigned*)(ws + 128);     // 256 x 8 u32 = 8 KB
  int* te   = (int*)(ws + 16640);
  int* tb   = (int*)(ws + 16640 + 4*MAXT);
  int* tl   = (int*)(ws + 16640 + 8*MAXT);
  int* perm = (int*)(ws + 32768);              // 256 KB
  short* wf0 = (short*)(ws + 294912);          // 8 e x 3 ks x 16 KB = 384 KB
  short* wf1 = (short*)(ws + 688128);          // 2 x 8 e x 8 ks x 16 KB = 2 MB

  k_prep<<<NHB + NPW, 256, 0, stream>>>(lab, W0, Wh, pcnt, wf0, wf1);
  k_route<<<NHB, 256, 0, stream>>>(lab, pcnt, perm, te, tb, tl, mu, lv, out + B_N);
  k_mlp<<<MAXT, 256, 0, stream>>>(x, eps, mu, lv, b0, bh, Wo, bo,
                                  wf0, wf1, perm, te, tb, tl, out);
}